// Round 13
// baseline (387.857 us; speedup 1.0000x reference)
//
#include <hip/hip_runtime.h>

// Problem constants: B=1, C=128, H=96, W=128
#define K_TOT 128
#define H_DIM 96
#define W_DIM 128
#define M_TOT (H_DIM * W_DIM)   // 12288
#define N_TOT (H_DIM * W_DIM)   // 12288
#define SCALE 4
#define NEG_INF (-3.402823e38f)

#define KP 384                  // folded K' = 3 x 128 sections
#define SLAB_F16 24576          // 64 rows x 384 k' f16 per slab

typedef _Float16 f16x8 __attribute__((ext_vector_type(8)));
typedef float f32x16 __attribute__((ext_vector_type(16)));

// async global->LDS, 16B/lane; LDS dest = wave-uniform base + lane*16
#define ASYNC16(lds_ptr, g_ptr) \
  __builtin_amdgcn_global_load_lds( \
      (const __attribute__((address_space(1))) unsigned int*)(g_ptr), \
      (__attribute__((address_space(3))) unsigned int*)(lds_ptr), 16, 0, 0)

// ---------------------------------------------------------------------------
// Prep: fp32 [K][P] -> f16 triplet in FRAG-MAJOR layout + fused keys-init.
//  x = h + l/64 with h=f16(x), l=f16((x-hf)*64)  (x-hf exact by Sterbenz)
//  k' sections: L: [h | h/64 | l]   R: [h | l | h/64]
//  => dot = h*h' + h*(y-h') + (x-h)*h'  (drop (x-h)(y-h') ~ 2^-22|xy|)
// Frag-major: slab s (64 rows), chunk c = half*128 + op*64 + hi*32 + col:
// 8 f16 at dst[s*24576 + c*8] = exactly lane (hi*32+col)'s MFMA operand bytes.
// 1536 blocks, each one (slab, k-quarter) -- 6 blocks/CU, latency-friendly.
// ---------------------------------------------------------------------------
__global__ __launch_bounds__(256)
void split_prep_kernel(const float* __restrict__ L, const float* __restrict__ R,
                       _Float16* __restrict__ Ls, _Float16* __restrict__ Rs,
                       unsigned long long* __restrict__ keys) {
    const int t = threadIdx.x;
    if (blockIdx.x >= 1536) {           // fused keys init (48 blocks)
        int m = (blockIdx.x - 1536) * 256 + t;
        if (m < M_TOT) keys[m] = 0ull;
        return;
    }
    __shared__ __align__(16) _Float16 T[3][64][40];   // planes: 0=h, 1=l, 2=h/64
    const int isR  = blockIdx.x >= 768;
    const int bb   = blockIdx.x - (isR ? 768 : 0);    // 0..767
    const int slab = bb >> 2;                         // 0..191
    const int q    = bb & 3;                          // k-quarter
    const int P0   = slab * 64;
    const int kq   = q * 32;
    const float* src = isR ? R : L;
    _Float16* dst = isR ? Rs : Ls;

    const int p4 = (t & 15) * 4;
    const int k0 = t >> 4;              // 0..15
#pragma unroll
    for (int it = 0; it < 2; ++it) {
        const int kl = k0 + it * 16;    // local k 0..31
        float4 v = *(const float4*)&src[(size_t)(kq + kl) * M_TOT + P0 + p4];
        float xs[4] = {v.x, v.y, v.z, v.w};
#pragma unroll
        for (int j = 0; j < 4; ++j) {
            _Float16 h = (_Float16)xs[j];
            float hf = (float)h;
            float r = xs[j] - hf;                    // exact
            T[0][p4 + j][kl] = h;
            T[1][p4 + j][kl] = (_Float16)(r * 64.0f);
            T[2][p4 + j][kl] = (_Float16)(hf * 0.015625f);  // h/64 (exact exp shift)
        }
    }
    __syncthreads();
    // 768 16B chunks for this (slab, quarter): u = sec*256 + jj*128 + op*64 + hi*32 + col
#pragma unroll
    for (int it = 0; it < 3; ++it) {
        const int u   = it * 256 + t;   // 0..767
        const int col = u & 31;
        const int hi  = (u >> 5) & 1;
        const int op  = (u >> 6) & 1;
        const int jj  = (u >> 7) & 1;
        const int sec = u >> 8;         // 0..2
        const int half   = sec * 8 + 2 * q + jj;
        const int c      = half * 128 + op * 64 + hi * 32 + col;
        const int klocal = jj * 16 + hi * 8;     // within our 32-k window
        const int plane  = (sec == 0) ? 0 : (isR ? sec : 3 - sec);
        const int row    = op * 32 + col;
        float4 v = *(const float4*)&T[plane][row][klocal];
        *(float4*)&dst[(size_t)slab * SLAB_F16 + (size_t)c * 8] = v;
    }
}

// ---------------------------------------------------------------------------
// Main (r13): traffic-halved A-in-LDS design. Block = 4 waves = ONE 64-row
// A slab staged ONCE into LDS (48KB, linear frag-major via global_load_lds);
// wave wid sweeps 12 B-slabs (q*48 + wid + 4j) x 24 halves = 288 iters, B
// direct global->VGPR (frag-major, 1KB/wave/iter), depth-2 prefetch, NO
// barriers in the loop. Grid 768 = 192 mt x 4 quarters, ALL co-resident
// (3 blocks/CU); XCD bid&7 -> quarter (bid&7)&3 => per-XCD B footprint
// 2.3MB, L2-resident. Rationale: r9-r12 counters fit an L2-port traffic
// wall (~20 TB/s): 3.6GB global reads -> 184us predicted ~= 160 measured.
// This halves global traffic to 1.8GB => ~90us bound.
// Per-nt argmax folds into registers (rbv[32] + byte-packed j/ni codes);
// single epilogue at the end.
// ---------------------------------------------------------------------------
__global__ __launch_bounds__(256, 3)
void mfma_corr_kernel(const _Float16* __restrict__ Ls, const _Float16* __restrict__ Rs,
                      unsigned long long* __restrict__ keys) {
    __shared__ __align__(16) char smem[49152];   // A slab; reused for reduce

    const int tid  = threadIdx.x;
    const int lane = tid & 63;
    const int wid  = tid >> 6;      // 0..3
    const int col  = lane & 31;
    const int hi   = lane >> 5;
    const int bid  = blockIdx.x;
    const int xcd  = bid & 7;
    const int q    = xcd & 3;                        // B quarter (48 slabs)
    const int mt   = ((bid >> 3) << 1) + (xcd >> 2); // 0..191, bijective
    const int m0   = mt * 64;

    // ---- stage A slab (48KB) into LDS, linear frag-major ----
#pragma unroll
    for (int i = 0; i < 12; ++i) {
        const int chunk = wid * 12 + i;              // 0..47 x 1024B
        ASYNC16(smem + chunk * 1024,
                Ls + (size_t)mt * SLAB_F16 + chunk * 512 + lane * 8);
    }
    __syncthreads();   // drains vmcnt: A visible to all waves

    float    rbv[32];
    unsigned rcw[8] = {0, 0, 0, 0, 0, 0, 0, 0};      // byte-packed codes j*2+ni
#pragma unroll
    for (int e = 0; e < 32; ++e) rbv[e] = NEG_INF;

    f32x16 acc[2][2];
#pragma unroll
    for (int mi = 0; mi < 2; ++mi)
#pragma unroll
        for (int ni = 0; ni < 2; ++ni) acc[mi][ni] = (f32x16)(0.0f);

    const _Float16* pB = Rs + (size_t)(q * 48 + wid) * SLAB_F16 + lane * 8;
    f16x8 fB[3][2];
    fB[0][0] = *(const f16x8*)(pB);
    fB[0][1] = *(const f16x8*)(pB + 512);
    fB[1][0] = *(const f16x8*)(pB + 1024);
    fB[1][1] = *(const f16x8*)(pB + 1536);

    for (int j = 0; j < 12; ++j) {
        const _Float16* pBn = pB + (size_t)4 * SLAB_F16;   // next j (stride 4 slabs)
#pragma unroll
        for (int h = 0; h < 24; ++h) {
            // depth-2 prefetch of flat-iter +2 (crosses into next j at h>=22)
            if (j < 11 || h < 22) {
                const _Float16* ps = (h < 22) ? (pB + (h + 2) * 1024)
                                              : (pBn + (h - 22) * 1024);
                const int s2 = (h + 2) % 3;          // 24%3==0 => slot pattern stable
                fB[s2][0] = *(const f16x8*)(ps);
                fB[s2][1] = *(const f16x8*)(ps + 512);
            }
            const int s = h % 3;
            f16x8 a0 = *(const f16x8*)(smem + h * 2048 + lane * 16);
            f16x8 a1 = *(const f16x8*)(smem + h * 2048 + 1024 + lane * 16);
            __builtin_amdgcn_s_setprio(1);
            acc[0][0] = __builtin_amdgcn_mfma_f32_32x32x16_f16(a0, fB[s][0], acc[0][0], 0, 0, 0);
            acc[0][1] = __builtin_amdgcn_mfma_f32_32x32x16_f16(a0, fB[s][1], acc[0][1], 0, 0, 0);
            acc[1][0] = __builtin_amdgcn_mfma_f32_32x32x16_f16(a1, fB[s][0], acc[1][0], 0, 0, 0);
            acc[1][1] = __builtin_amdgcn_mfma_f32_32x32x16_f16(a1, fB[s][1], acc[1][1], 0, 0, 0);
            __builtin_amdgcn_s_setprio(0);
        }
        // fold nt j into running per-row best (ni inner, j ascending => first-
        // occurrence kept by strict >); reset acc for next j
        const unsigned cj = (unsigned)(j << 1);
#pragma unroll
        for (int mi = 0; mi < 2; ++mi)
#pragma unroll
            for (int reg = 0; reg < 16; ++reg) {
                const int e = mi * 16 + reg;
                float v0 = acc[mi][0][reg], v1 = acc[mi][1][reg];
                const bool sel = v1 > v0;            // tie keeps ni=0 (smaller n)
                float v = sel ? v1 : v0;
                unsigned code = cj | (sel ? 1u : 0u);
                if (v > rbv[e]) {
                    rbv[e] = v;
                    const int w = e >> 2, sh = (e & 3) * 8;
                    rcw[w] = (rcw[w] & ~(255u << sh)) | (code << sh);
                }
                acc[mi][0][reg] = 0.0f;
                acc[mi][1][reg] = 0.0f;
            }
        pB = pBn;
    }

    // --- epilogue ---
    // C/D 32x32 layout: col = lane&31, row = (reg&3) + 8*(reg>>2) + 4*(lane>>5)
    __syncthreads();   // all waves done reading A region -> reuse for reduce
    float* vals = (float*)smem;            // [64][33] floats = 8448 B
    int*   idxs = (int*)(smem + 8448);     // 8448 B
#pragma unroll
    for (int mi = 0; mi < 2; ++mi)
#pragma unroll
        for (int reg = 0; reg < 16; ++reg) {
            const int e = mi * 16 + reg;
            float best = rbv[e];
            const unsigned code = (rcw[e >> 2] >> ((e & 3) * 8)) & 255u;
            int n = (q * 48 + wid + 4 * (int)(code >> 1)) * 64 + (int)(code & 1) * 32 + col;
#pragma unroll
            for (int d = 16; d >= 8; d >>= 1) {      // fold cols ^16 then ^8
                float ov = __shfl_xor(best, d, 64);
                int   oi = __shfl_xor(n, d, 64);
                if (ov > best || (ov == best && oi < n)) { best = ov; n = oi; }
            }
            if ((lane & 24) == 0) {
                const int row = mi * 32 + (reg & 3) + 8 * (reg >> 2) + 4 * hi;
                const int c   = wid * 8 + (lane & 7);
                vals[row * 33 + c] = best;
                idxs[row * 33 + c] = n;
            }
        }
    __syncthreads();
    if (tid < 64) {
        float bv = vals[tid * 33 + 0]; int bi = idxs[tid * 33 + 0];
#pragma unroll
        for (int c = 1; c < 32; ++c) {
            float v = vals[tid * 33 + c]; int ix = idxs[tid * 33 + c];
            if (v > bv || (v == bv && ix < bi)) { bv = v; bi = ix; }
        }
        unsigned vb = __float_as_uint(bv);
        vb = (vb & 0x80000000u) ? ~vb : (vb | 0x80000000u);
        unsigned long long key = ((unsigned long long)vb << 32) | (unsigned)(~bi);
        atomicMax(&keys[m0 + tid], key);
    }
}

// decode keys -> flow + cost
__global__ void finalize_keys_kernel(const unsigned long long* __restrict__ keys,
                                     float* __restrict__ out) {
    int m = blockIdx.x * blockDim.x + threadIdx.x;
    if (m >= M_TOT) return;
    unsigned long long key = keys[m];
    unsigned hi = (unsigned)(key >> 32);
    unsigned bits = (hi & 0x80000000u) ? (hi & 0x7fffffffu) : ~hi;
    float v = __uint_as_float(bits);
    int idx = (int)(~(unsigned)(key & 0xffffffffu));
    int h = m / W_DIM, w = m % W_DIM;
    int i = idx / W_DIM, j = idx % W_DIM;
    out[m * 2 + 0] = (float)(w - SCALE * j);
    out[m * 2 + 1] = (float)(h - SCALE * i);
    out[2 * M_TOT + m] = v;
}

// ---------------------------------------------------------------------------
// Fallback fp32 VALU path in case ws_size is too small.
// ---------------------------------------------------------------------------
#define BM 128
#define BN 128
#define KB 32
__global__ __launch_bounds__(256)
void corr_argmax_kernel(const float* __restrict__ L, const float* __restrict__ R,
                        float* __restrict__ pbest, int* __restrict__ pidx,
                        int nsplit) {
    __shared__ float As[KB][BM];
    __shared__ float Bs[KB][BN];
    const int tid = threadIdx.x;
    const int mtiles = M_TOT / BM;
    const int mt = blockIdx.x % mtiles;
    const int s  = blockIdx.x / mtiles;
    const int m0 = mt * BM;
    const int ns = N_TOT / nsplit;
    const int ntiles = ns / BN;
    const int tx = tid & 15;
    const int ty = tid >> 4;
    float rbest[8]; int ridx[8];
#pragma unroll
    for (int i = 0; i < 8; ++i) { rbest[i] = NEG_INF; ridx[i] = 0; }
    for (int nt = 0; nt < ntiles; ++nt) {
        const int n0 = s * ns + nt * BN;
        float acc[8][8];
#pragma unroll
        for (int i = 0; i < 8; ++i)
#pragma unroll
            for (int j = 0; j < 8; ++j) acc[i][j] = 0.f;
        for (int kb = 0; kb < K_TOT; kb += KB) {
            __syncthreads();
#pragma unroll
            for (int r = 0; r < 4; ++r) {
                int f  = tid + 256 * r;
                int kk = f >> 5;
                int c4 = f & 31;
                float4 va = *reinterpret_cast<const float4*>(&L[(size_t)(kb + kk) * M_TOT + m0 + c4 * 4]);
                *reinterpret_cast<float4*>(&As[kk][c4 * 4]) = va;
                float4 vb = *reinterpret_cast<const float4*>(&R[(size_t)(kb + kk) * N_TOT + n0 + c4 * 4]);
                *reinterpret_cast<float4*>(&Bs[kk][c4 * 4]) = vb;
            }
            __syncthreads();
#pragma unroll 4
            for (int kk = 0; kk < KB; ++kk) {
                float4 a0 = *reinterpret_cast<const float4*>(&As[kk][ty * 4]);
                float4 a1 = *reinterpret_cast<const float4*>(&As[kk][64 + ty * 4]);
                float4 b0 = *reinterpret_cast<const float4*>(&Bs[kk][tx * 4]);
                float4 b1 = *reinterpret_cast<const float4*>(&Bs[kk][64 + tx * 4]);
                float a[8] = {a0.x, a0.y, a0.z, a0.w, a1.x, a1.y, a1.z, a1.w};
                float b[8] = {b0.x, b0.y, b0.z, b0.w, b1.x, b1.y, b1.z, b1.w};
#pragma unroll
                for (int i = 0; i < 8; ++i)
#pragma unroll
                    for (int j = 0; j < 8; ++j)
                        acc[i][j] = fmaf(a[i], b[j], acc[i][j]);
            }
        }
#pragma unroll
        for (int i = 0; i < 8; ++i)
#pragma unroll
            for (int jh = 0; jh < 2; ++jh)
#pragma unroll
                for (int jj = 0; jj < 4; ++jj) {
                    int n = n0 + jh * 64 + tx * 4 + jj;
                    float v = acc[i][jh * 4 + jj];
                    if (v > rbest[i]) { rbest[i] = v; ridx[i] = n; }
                }
    }
    __syncthreads();
    float (*redv)[BM] = reinterpret_cast<float(*)[BM]>(&As[0][0]);
    int   (*redi)[BM] = reinterpret_cast<int  (*)[BM]>(&Bs[0][0]);
#pragma unroll
    for (int i = 0; i < 8; ++i) {
        int row = (i >> 2) * 64 + ty * 4 + (i & 3);
        redv[tx][row] = rbest[i];
        redi[tx][row] = ridx[i];
    }
    __syncthreads();
    if (tid < BM) {
        float bv = NEG_INF; int bi = 0x7fffffff;
        for (int t = 0; t < 16; ++t) {
            float v  = redv[t][tid];
            int   ix = redi[t][tid];
            if (v > bv || (v == bv && ix < bi)) { bv = v; bi = ix; }
        }
        pbest[(size_t)s * M_TOT + m0 + tid] = bv;
        pidx [(size_t)s * M_TOT + m0 + tid] = bi;
    }
}

__global__ void finalize_parts_kernel(const float* __restrict__ pbest,
                                      const int* __restrict__ pidx,
                                      float* __restrict__ out, int nsplit) {
    int m = blockIdx.x * blockDim.x + threadIdx.x;
    if (m >= M_TOT) return;
    float bv = NEG_INF; int bi = 0x7fffffff;
    for (int s = 0; s < nsplit; ++s) {
        float v  = pbest[(size_t)s * M_TOT + m];
        int   ix = pidx [(size_t)s * M_TOT + m];
        if (v > bv || (v == bv && ix < bi)) { bv = v; bi = ix; }
    }
    int h = m / W_DIM, w = m % W_DIM;
    int i = bi / W_DIM, j = bi % W_DIM;
    out[m * 2 + 0] = (float)(w - SCALE * j);
    out[m * 2 + 1] = (float)(h - SCALE * i);
    out[2 * M_TOT + m] = bv;
}

extern "C" void kernel_launch(void* const* d_in, const int* in_sizes, int n_in,
                              void* d_out, int out_size, void* d_ws, size_t ws_size,
                              hipStream_t stream) {
    const float* L = (const float*)d_in[0];
    const float* R = (const float*)d_in[1];
    float* out = (float*)d_out;

    const size_t PKbytes = (size_t)M_TOT * KP * sizeof(_Float16);   // 9.44 MB
    const size_t need = 2 * PKbytes + (size_t)M_TOT * 8;            // ~19 MB
    if (ws_size >= need) {
        _Float16* Ls = (_Float16*)d_ws;
        _Float16* Rs = (_Float16*)((char*)d_ws + PKbytes);
        unsigned long long* keys = (unsigned long long*)((char*)d_ws + 2 * PKbytes);
        split_prep_kernel<<<dim3(1584), dim3(256), 0, stream>>>(L, R, Ls, Rs, keys);
        mfma_corr_kernel<<<dim3(768), dim3(256), 0, stream>>>(Ls, Rs, keys);
        finalize_keys_kernel<<<dim3(48), dim3(256), 0, stream>>>(keys, out);
    } else {
        int nsplit = 8;
        while (nsplit > 1 && (size_t)nsplit * M_TOT * 8 > ws_size) nsplit >>= 1;
        float* pbest = (float*)d_ws;
        int*   pidx  = (int*)((char*)d_ws + (size_t)nsplit * M_TOT * sizeof(float));
        corr_argmax_kernel<<<dim3((M_TOT / BM) * nsplit), dim3(256), 0, stream>>>(L, R, pbest, pidx, nsplit);
        finalize_parts_kernel<<<dim3((M_TOT + 255) / 256), dim3(256), 0, stream>>>(pbest, pidx, out, nsplit);
    }
}